// Round 18
// baseline (3612.526 us; speedup 1.0000x reference)
//
#include <hip/hip_runtime.h>
#include <stdint.h>

typedef unsigned short u16;

#define T_STEPS 512
#define BATCH   64
#define DIN     512
#define HID     1024
#define G4      4096
#define NBLK    64      // 64 blocks x 16 units -> HALF the h-broadcast traffic
#define NH      16      // hidden units per block
#define NC      64      // gate cols per block; col c = u_local*4 + gate
#define THREADS 512

#define U_LD    1032    // 1024 + 8 pad (init staging only)
#define W_LD    520     // 512 + 8 pad  (init staging only)

// LDS: init  stage[32][U_LD] (66048B, 2 passes U then 2 passes W)
//      run   zp f32[8][32][68] (69632B, aliases dead staging)
#define SM_BYTES 69632

// ws map
#define XB_BYTES ((size_t)T_STEPS * BATCH * DIN * 2)   // 32 MB bf16 x
#define HB_OFF   XB_BYTES    // h bf16: [ch2][par2][kblk64][row32][u16]
#define HB_PAR   65536       // one parity buffer = 64*32*16*2
#define HB_CH    (2 * HB_PAR)
#define HB_BYTES (2u * HB_CH)                          // 256 KB
#define FLG_OFF  (HB_OFF + HB_BYTES)                   // flags [ch2][blk64] x 16B
#define FLG_BYTES (2 * 64 * 16)
#define WS_NEED  (FLG_OFF + FLG_BYTES)

typedef float f32x16 __attribute__((ext_vector_type(16)));
typedef short bf16x8 __attribute__((ext_vector_type(8)));
typedef unsigned uint32x4 __attribute__((ext_vector_type(4)));

__device__ __forceinline__ u16 f2bf(float f) {
  unsigned u = __float_as_uint(f);
  u += 0x7fffu + ((u >> 16) & 1u);   // RNE
  return (u16)(u >> 16);
}
__device__ __forceinline__ float sigm(float x) {
  return __builtin_amdgcn_rcpf(1.f + __expf(-x));
}
__device__ __forceinline__ float fast_tanh(float x) {
  return 1.f - 2.f * __builtin_amdgcn_rcpf(__expf(2.f * x) + 1.f);
}

// sc0 sc1 = coherence-point access (bypass L1/L2); flat 64b VGPR address.
__device__ __forceinline__ uint32x4 load16_sc(uint64_t addr) {
  uint32x4 d;
  asm volatile("global_load_dwordx4 %0, %1, off sc0 sc1" : "=v"(d) : "v"(addr));
  return d;
}
__device__ __forceinline__ uint32x4 load16_plain(uint64_t addr) {
  uint32x4 d;
  asm volatile("global_load_dwordx4 %0, %1, off" : "=v"(d) : "v"(addr));
  return d;
}
__device__ __forceinline__ unsigned load4_sc(uint64_t addr) {
  unsigned d;
  asm volatile("global_load_dword %0, %1, off sc0 sc1" : "=v"(d) : "v"(addr));
  return d;
}
__device__ __forceinline__ void store16_sc(uint64_t addr, uint32x4 v) {
  asm volatile("global_store_dwordx4 %0, %1, off sc0 sc1" :: "v"(addr), "v"(v) : "memory");
}
__device__ __forceinline__ void store4_sc(uint64_t addr, unsigned v) {
  asm volatile("global_store_dword %0, %1, off sc0 sc1" :: "v"(addr), "v"(v) : "memory");
}
#define WAITV(n) asm volatile("s_waitcnt vmcnt(" #n ")" ::: "memory")
#define SBAR()   __builtin_amdgcn_sched_barrier(0)

// x[B][T][D] fp32 -> xb[T][B][D] bf16
__global__ void cvt_x(const float* __restrict__ x, u16* __restrict__ xb) {
  int i = blockIdx.x * 256 + threadIdx.x;
  int dblk = i & 63;
  int rest = i >> 6;
  int b = rest & 63;
  int t = rest >> 6;
  const float4* s = reinterpret_cast<const float4*>(x + ((size_t)(b * T_STEPS + t)) * DIN + dblk * 8);
  float4 f0 = s[0], f1 = s[1];
  uint4 o;
  o.x = (unsigned)f2bf(f0.x) | ((unsigned)f2bf(f0.y) << 16);
  o.y = (unsigned)f2bf(f0.z) | ((unsigned)f2bf(f0.w) << 16);
  o.z = (unsigned)f2bf(f1.x) | ((unsigned)f2bf(f1.y) << 16);
  o.w = (unsigned)f2bf(f1.z) | ((unsigned)f2bf(f1.w) << 16);
  *reinterpret_cast<uint4*>(xb + ((size_t)(t * BATCH + b)) * DIN + dblk * 8) = o;
}

// Dual-chain persistent LSTM, 64 blocks x 16 units (half the h-broadcast of
// the 128-block design; these kernels are coherence-point BANDWIDTH-bound).
// Per phase: M=32 (one batch half), N=64 gate-interleaved cols, K=1536.
// 8 waves = 8 exclusive K-splits (128 HID + 64 DIN each); each wave covers
// N as 2 N-tiles SHARING its A-fragments (A-reads stay 1x). zp 8-way reduce.
// Protocol = r15 (proven at its traffic floor): publish(shfl-pack, full-line)
// -> per-wave ack -> barrier -> block flag -> poll next chain -> prefetch.
__launch_bounds__(THREADS, 2)
__global__ void lstm_kernel(const float* __restrict__ W, const float* __restrict__ U,
                            const float* __restrict__ bias, const u16* __restrict__ xb,
                            char* __restrict__ ws, float* __restrict__ out) {
  __shared__ __align__(16) char smraw[SM_BYTES];
  u16* stage = (u16*)smraw;                        // init staging (2-pass)
  float (*zp)[32][68] = (float(*)[32][68])smraw;   // run phase

  const int tid = threadIdx.x;
  const int bid = blockIdx.x;
  const int j0 = bid * NH;

  const int l  = tid & 63;
  const int wv = tid >> 6;           // K-split 0..7
  const int cl = l & 31;             // A-row / B-col within tile
  const int q  = l >> 5;             // k-half

  // ---- init: 2-pass staged load of U cols then W cols; frags -> registers ----
  bf16x8 ubf[2][8], wbf[2][4];
#pragma unroll
  for (int ph = 0; ph < 2; ++ph) {
    for (int idx = tid; idx < 32 * HID; idx += THREADS) {
      int cc = idx & 31, k = idx >> 5;
      int c = ph * 32 + cc;
      int gcol = ((c & 3) << 10) + j0 + (c >> 2);
      stage[cc * U_LD + k] = f2bf(U[(size_t)k * G4 + gcol]);
    }
    __syncthreads();
    {
      const u16* ub = stage + cl * U_LD + wv * 128 + q * 8;
#pragma unroll
      for (int s = 0; s < 8; ++s) ubf[ph][s] = *(const bf16x8*)(ub + s * 16);
    }
    __syncthreads();
  }
#pragma unroll
  for (int ph = 0; ph < 2; ++ph) {
    for (int idx = tid; idx < 32 * DIN; idx += THREADS) {
      int cc = idx & 31, k = idx >> 5;
      int c = ph * 32 + cc;
      int gcol = ((c & 3) << 10) + j0 + (c >> 2);
      stage[cc * W_LD + k] = f2bf(W[(size_t)k * G4 + gcol]);
    }
    __syncthreads();
    {
      const u16* wb = stage + cl * W_LD + wv * 64 + q * 8;
#pragma unroll
      for (int s = 0; s < 4; ++s) wbf[ph][s] = *(const bf16x8*)(wb + s * 16);
    }
    __syncthreads();
  }
  // staging dead; zp live from here

  // gates: thread -> (row pb, unit pu); all 512 threads active
  const int pb = tid >> 4;           // 0..31
  const int pu = tid & 15;           // 0..15
  const float bi  = bias[j0 + pu];
  const float bf_ = bias[1024 + j0 + pu];
  const float bg  = bias[2048 + j0 + pu];
  const float bo  = bias[3072 + j0 + pu];
  float cA = 0.f, cB = 0.f;
  int alive = 1;

  const uint64_t hbase = (uint64_t)ws + HB_OFF;
  const uint64_t fbase = (uint64_t)ws + FLG_OFF;
  const uint64_t xb64  = (uint64_t)xb;
  // consumer lane base (within parity buf): kblk = wv*8 + s; addr = kblk*1024
  // + row*32 + (k&15)*2 with k&15 = q*8
  const uint64_t hlane = (uint64_t)wv * 8192 + (uint64_t)cl * 32 + (uint64_t)q * 16;
  // publisher leader (l&7)==0: row tid>>4, unit-half (l>>3)&1
  const uint64_t puboff = (uint64_t)bid * 1024 + (uint64_t)(tid >> 4) * 32 +
                          (uint64_t)((l >> 3) & 1) * 16;
  // poll: lane l watches producer block l's flag
  const uint64_t pollo = (uint64_t)l * 16;

  uint32x4 hbuf[8], xr[4];

#define ISSUE_BUNDLE(NCH, NT) do {                                               \
    const uint64_t hb_ = hbase + (uint64_t)(NCH) * HB_CH +                       \
                         (uint64_t)((NT) & 1) * HB_PAR + hlane;                  \
    _Pragma("unroll")                                                            \
    for (int s_ = 0; s_ < 8; ++s_) hbuf[s_] = load16_sc(hb_ + (uint64_t)s_ * 1024); \
    const uint64_t xa_ = xb64 + (((uint64_t)(NT) * 64 + (NCH) * 32 + cl) * 512   \
                                 + (uint64_t)(wv * 64 + q * 8)) * 2;             \
    _Pragma("unroll")                                                            \
    for (int s_ = 0; s_ < 4; ++s_) xr[s_] = load16_plain(xa_ + (uint64_t)s_ * 32); \
  } while (0)

#define PHASE(CH, TT, CREG, OCH, OT) do {                                        \
    WAITV(0); SBAR();   /* drain prefetched hbuf/xr (+ stray flag store) */      \
    f32x16 acc0 = {0.f,0.f,0.f,0.f,0.f,0.f,0.f,0.f,0.f,0.f,0.f,0.f,0.f,0.f,0.f,0.f}; \
    f32x16 acc1 = {0.f,0.f,0.f,0.f,0.f,0.f,0.f,0.f,0.f,0.f,0.f,0.f,0.f,0.f,0.f,0.f}; \
    _Pragma("unroll")                                                            \
    for (int s_ = 0; s_ < 8; ++s_) {   /* h@U: same A feeds both N-tiles */      \
      bf16x8 a_ = __builtin_bit_cast(bf16x8, hbuf[s_]);                          \
      acc0 = __builtin_amdgcn_mfma_f32_32x32x16_bf16(a_, ubf[0][s_], acc0, 0, 0, 0); \
      acc1 = __builtin_amdgcn_mfma_f32_32x32x16_bf16(a_, ubf[1][s_], acc1, 0, 0, 0); \
    }                                                                            \
    _Pragma("unroll")                                                            \
    for (int s_ = 0; s_ < 4; ++s_) {   /* x@W */                                 \
      bf16x8 a_ = __builtin_bit_cast(bf16x8, xr[s_]);                            \
      acc0 = __builtin_amdgcn_mfma_f32_32x32x16_bf16(a_, wbf[0][s_], acc0, 0, 0, 0); \
      acc1 = __builtin_amdgcn_mfma_f32_32x32x16_bf16(a_, wbf[1][s_], acc1, 0, 0, 0); \
    }                                                                            \
    _Pragma("unroll")                                                            \
    for (int r_ = 0; r_ < 16; ++r_) {  /* C: col=cl, row=(r&3)+8*(r>>2)+4q */    \
      int rl_ = (r_ & 3) + 8 * (r_ >> 2) + 4 * q;                                \
      zp[wv][rl_][cl]      = acc0[r_];                                           \
      zp[wv][rl_][32 + cl] = acc1[r_];                                           \
    }                                                                            \
    __syncthreads();   /* b1: zp write -> read */                                \
    {                                                                            \
      float zi = bi, zf = bf_, zg = bg, zo = bo;                                 \
      _Pragma("unroll")                                                          \
      for (int k2 = 0; k2 < 8; ++k2) {                                           \
        float4 v = *(const float4*)&zp[k2][pb][pu * 4];                          \
        zi += v.x; zf += v.y; zg += v.z; zo += v.w;                              \
      }                                                                          \
      float ig = sigm(zi), fg = sigm(zf), og = sigm(zo);                         \
      float gg = fast_tanh(zg);                                                  \
      CREG = fg * CREG + ig * gg;                                                \
      float h = og * fast_tanh(CREG);                                            \
      unsigned hval = (unsigned)f2bf(h);                                         \
      unsigned other = __shfl_xor(hval, 1);                                      \
      unsigned pair32 = (l & 1) ? ((other & 0xffffu) | (hval << 16))             \
                                : ((hval & 0xffffu) | (other << 16));            \
      int base_ = l & ~7;                                                        \
      uint32x4 hv;                                                               \
      hv[0] = __shfl(pair32, base_);     hv[1] = __shfl(pair32, base_ + 2);      \
      hv[2] = __shfl(pair32, base_ + 4); hv[3] = __shfl(pair32, base_ + 6);      \
      if ((l & 7) == 0)                                                          \
        store16_sc(hbase + (uint64_t)(CH) * HB_CH +                              \
                   (uint64_t)(((TT) + 1) & 1) * HB_PAR + puboff, hv);            \
      if ((TT) == T_STEPS - 1) {                                                 \
        float* orow = out + (size_t)((CH) * 32 + pb) * 3072 + j0 + pu;           \
        orow[0] = h; orow[1024] = h; orow[2048] = CREG;                          \
      }                                                                          \
    }                                                                            \
    WAITV(0);          /* per-wave: own publish (+ epilogue) acked */            \
    __syncthreads();   /* b2: ALL waves' publishes acked; zp reads done */       \
    if (tid == 0)      /* whole-block flag */                                    \
      store4_sc(fbase + (uint64_t)(CH) * 1024 + (uint64_t)bid * 16,              \
                (unsigned)((TT) + 1));                                           \
    if (alive) {       /* poll next chain's 64 producers (1 flag per lane) */    \
      const uint64_t fa = fbase + (uint64_t)(OCH) * 1024 + pollo;                \
      int spins = 0;                                                             \
      while (true) {                                                             \
        unsigned f = load4_sc(fa);                                               \
        WAITV(0);                                                                \
        if (__all(f >= (unsigned)(OT))) break;                                   \
        if (++spins > (1 << 20)) { alive = 0; break; }                           \
        __builtin_amdgcn_s_sleep(1);                                             \
      }                                                                          \
    }                                                                            \
    ISSUE_BUNDLE(OCH, OT);   /* flag-certified fresh prefetch */                 \
  } while (0)

  // bootstrap: flags memset 0 => (A,0) ready; h parity 0 zeros = h_0
  ISSUE_BUNDLE(0, 0);

  for (int t = 0; t < T_STEPS; ++t) {
    const int tn = (t + 1 < T_STEPS) ? (t + 1) : (T_STEPS - 1);
    PHASE(0, t, cA, 1, t);    // next = (B, t)
    PHASE(1, t, cB, 0, tn);   // next = (A, t+1) (clamped on last iter)
  }
#undef PHASE
#undef ISSUE_BUNDLE
}

extern "C" void kernel_launch(void* const* d_in, const int* in_sizes, int n_in,
                              void* d_out, int out_size, void* d_ws, size_t ws_size,
                              hipStream_t stream) {
  const float* x = (const float*)d_in[0];
  const float* W = (const float*)d_in[1];
  const float* U = (const float*)d_in[2];
  const float* b = (const float*)d_in[3];
  float* out = (float*)d_out;

  if (ws_size < WS_NEED) return;  // loud failure: output stays poisoned

  u16* xb = (u16*)d_ws;
  // zero h (both chains/parities) + flags — replayed every graph launch
  hipMemsetAsync((char*)d_ws + HB_OFF, 0, HB_BYTES + FLG_BYTES, stream);
  cvt_x<<<(T_STEPS * BATCH * DIN / 8 + 255) / 256, 256, 0, stream>>>(x, xb);
  lstm_kernel<<<NBLK, THREADS, 0, stream>>>(W, U, b, xb, (char*)d_ws, out);
}

// Round 19
// 2537.978 us; speedup vs baseline: 1.4234x; 1.4234x over previous
//
#include <hip/hip_runtime.h>
#include <stdint.h>

typedef unsigned short u16;

#define T_STEPS 512
#define BATCH   64
#define DIN     512
#define HID     1024
#define G4      4096
#define NBLK    128
#define NH      8       // hidden units per block
#define NC      32      // gate columns per block (4*NH)
#define THREADS 512

#define U_LD    1032    // 1024 + 8 pad (init staging only)
#define W_LD    520     // 512 + 8 pad  (init staging only)

// LDS: init phase  Ut[NC*U_LD] @0 (66048B), Wt[NC*W_LD] @66048 (33280B)
//      run  phase  zpart f32[4][64][33] @0 (33792B)
#define SM_BYTES 99328
#define WT_OFF   66048

// ws map
#define XB_BYTES ((size_t)T_STEPS * BATCH * DIN * 2)   // 32 MB bf16 x
#define HB_OFF   XB_BYTES        // rolling h slabs: [slot128][kblk128][row64][8u] bf16
#define SLAB     131072          // one slab = BATCH*HID*2 = 128 KB
#define NSLOT    128             // write-once window; reuse after 128 steps
#define HB_BYTES ((size_t)NSLOT * SLAB)                // 16 MB
#define FLG_OFF  (HB_OFF + HB_BYTES)                   // 128 flags x 16B
#define FLG_BYTES 2048
#define WS_NEED  (FLG_OFF + FLG_BYTES)

typedef float f32x16 __attribute__((ext_vector_type(16)));
typedef short bf16x8 __attribute__((ext_vector_type(8)));
typedef unsigned uint32x4 __attribute__((ext_vector_type(4)));

__device__ __forceinline__ u16 f2bf(float f) {
  unsigned u = __float_as_uint(f);
  u += 0x7fffu + ((u >> 16) & 1u);   // RNE
  return (u16)(u >> 16);
}
__device__ __forceinline__ float sigm(float x) {
  return __builtin_amdgcn_rcpf(1.f + __expf(-x));
}
__device__ __forceinline__ float fast_tanh(float x) {
  return 1.f - 2.f * __builtin_amdgcn_rcpf(__expf(2.f * x) + 1.f);
}

// sc0 sc1 = coherence-point access (bypass L1/L2) — used for publish + flags.
// plain    = normal cached load — used for h reads (write-once slabs make it safe).
__device__ __forceinline__ uint32x4 load16_plain(uint64_t addr) {
  uint32x4 d;
  asm volatile("global_load_dwordx4 %0, %1, off" : "=v"(d) : "v"(addr));
  return d;
}
__device__ __forceinline__ unsigned load4_sc(uint64_t addr) {
  unsigned d;
  asm volatile("global_load_dword %0, %1, off sc0 sc1" : "=v"(d) : "v"(addr));
  return d;
}
__device__ __forceinline__ void store16_sc(uint64_t addr, uint32x4 v) {
  asm volatile("global_store_dwordx4 %0, %1, off sc0 sc1" :: "v"(addr), "v"(v) : "memory");
}
__device__ __forceinline__ void store4_sc(uint64_t addr, unsigned v) {
  asm volatile("global_store_dword %0, %1, off sc0 sc1" :: "v"(addr), "v"(v) : "memory");
}
#define WAITV(n) asm volatile("s_waitcnt vmcnt(" #n ")" ::: "memory")

// x[B][T][D] fp32 -> xb[T][B][D] bf16  (also: streams ~96 MB through the L2s
// every launch, flushing any cross-replay h-slab lines)
__global__ void cvt_x(const float* __restrict__ x, u16* __restrict__ xb) {
  int i = blockIdx.x * 256 + threadIdx.x;
  int dblk = i & 63;
  int rest = i >> 6;
  int b = rest & 63;
  int t = rest >> 6;
  const float4* s = reinterpret_cast<const float4*>(x + ((size_t)(b * T_STEPS + t)) * DIN + dblk * 8);
  float4 f0 = s[0], f1 = s[1];
  uint4 o;
  o.x = (unsigned)f2bf(f0.x) | ((unsigned)f2bf(f0.y) << 16);
  o.y = (unsigned)f2bf(f0.z) | ((unsigned)f2bf(f0.w) << 16);
  o.z = (unsigned)f2bf(f1.x) | ((unsigned)f2bf(f1.y) << 16);
  o.w = (unsigned)f2bf(f1.z) | ((unsigned)f2bf(f1.w) << 16);
  *reinterpret_cast<uint4*>(xb + ((size_t)(t * BATCH + b)) * DIN + dblk * 8) = o;
}

// Persistent LSTM (r14 skeleton). Block bid owns hidden units [bid*8, bid*8+8).
// GEMM: 32x32x16 MFMA, 8 waves = 2 M-tiles x 4 K-splits; B-frags in registers;
// K-split partials reduced through LDS (zp). Wave ks polls its 32 producers.
// NEW: h lives in WRITE-ONCE rolling slabs (slot = t mod 128) and consumers
// read it with PLAIN CACHED loads -> each XCD's L2 serves 15 of every 16
// reads; the coherence point sees 1 MB/step instead of 16 MB. Producers still
// publish sc1 (data at CP before flag), flags/polls stay sc1 (always fresh).
// Staleness-safe: slab reuse is 128 steps (~50 MB/XCD intervening traffic >>
// 4 MB L2); cross-replay leftovers are flushed by cvt_x and, regardless,
// bit-identical (deterministic kernel).
__launch_bounds__(THREADS)
__global__ void lstm_kernel(const float* __restrict__ W, const float* __restrict__ U,
                            const float* __restrict__ bias, const u16* __restrict__ xb,
                            char* __restrict__ ws, float* __restrict__ out) {
  __shared__ __align__(16) char smraw[SM_BYTES];
  u16* Ut = (u16*)smraw;
  u16* Wt = (u16*)(smraw + WT_OFF);
  float* zp = (float*)smraw;              // run phase: [4][64][33]

  const int tid = threadIdx.x;
  const int bid = blockIdx.x;
  const int j0 = bid * NH;

  // ---- init: stage transposed bf16 weight slices ----
  for (int idx = tid; idx < NC * HID; idx += THREADS) {
    int c = idx & (NC - 1);
    int k = idx >> 5;
    int gcol = ((c >> 3) << 10) + j0 + (c & 7);
    Ut[c * U_LD + k] = f2bf(U[(size_t)k * G4 + gcol]);
  }
  for (int idx = tid; idx < NC * DIN; idx += THREADS) {
    int c = idx & (NC - 1);
    int k = idx >> 5;
    int gcol = ((c >> 3) << 10) + j0 + (c & 7);
    Wt[c * W_LD + k] = f2bf(W[(size_t)k * G4 + gcol]);
  }
  __syncthreads();

  // ---- wave geometry: wv = (ks<<1)|m_t ----
  const int l   = tid & 63;
  const int wv  = tid >> 6;
  const int m_t = wv & 1;          // batch rows m_t*32 .. +31
  const int ks  = wv >> 1;         // K-split 0..3 (256 of HID, 128 of DIN each)
  const int cl  = l & 31;          // A row within tile / B column
  const int q   = l >> 5;          // k-half of fragment

  // ---- persistent B fragments -> registers ----
  bf16x8 ubf[16], wbf[8];
  {
    const u16* ub = Ut + cl * U_LD + ks * 256 + q * 8;
#pragma unroll
    for (int s = 0; s < 16; ++s) ubf[s] = *(const bf16x8*)(ub + s * 16);
    const u16* wb = Wt + cl * W_LD + ks * 128 + q * 8;
#pragma unroll
    for (int s = 0; s < 8; ++s) wbf[s] = *(const bf16x8*)(wb + s * 16);
  }
  __syncthreads();   // staging dead; zp live from here

  const int row = m_t * 32 + cl;   // batch row this lane loads for A
  // gates: thread -> (row pb, unit pu); pu in low bits so a wave's 64 lanes
  // cover 8 consecutive rows x 8 units = one contiguous 128B publish slice
  const int pb = tid >> 3;
  const int pu = tid & 7;
  float c_reg = 0.f;
  const float bi  = bias[j0 + pu];
  const float bf_ = bias[1024 + j0 + pu];
  const float bg  = bias[2048 + j0 + pu];
  const float bo  = bias[3072 + j0 + pu];

  const uint64_t hbB   = (uint64_t)ws + HB_OFF;
  const uint64_t fbase = (uint64_t)ws + FLG_OFF;
  // per-lane poll address: the ONE producer flag this lane's wave-k-slice needs
  const uint64_t faddr = fbase + (uint64_t)(ks * 32 + cl) * 16;
  // h A-frag: kblk = ks*32 + s*2 + q, byte = kblk*1024 + row*16
  const uint64_t hlane = (uint64_t)(ks * 32 + q) * 1024 + (uint64_t)row * 16;
  // publish: leader lanes (l&7)==0 store 16B of row wv*8 + (l>>3)
  const uint64_t puboff = (uint64_t)bid * 1024 + (uint64_t)(wv * 8 + (l >> 3)) * 16;

#define HMFMA(S) acc = __builtin_amdgcn_mfma_f32_32x32x16_bf16( \
    __builtin_bit_cast(bf16x8, abuf[S]), ubf[S], acc, 0, 0, 0)

  for (int t = 0; t < T_STEPS; ++t) {
    f32x16 acc = {0.f,0.f,0.f,0.f,0.f,0.f,0.f,0.f,0.f,0.f,0.f,0.f,0.f,0.f,0.f,0.f};

    // ---- x_t @ W (cached loads; overlaps other blocks finishing t-1) ----
    const u16* xa = xb + (size_t)t * (BATCH * DIN) + row * DIN + ks * 128 + q * 8;
#pragma unroll
    for (int s = 0; s < 8; ++s) {
      bf16x8 av = *(const bf16x8*)(xa + s * 16);
      acc = __builtin_amdgcn_mfma_f32_32x32x16_bf16(av, wbf[s], acc, 0, 0, 0);
    }

    // ---- fine-grained poll: one flag per lane, this wave's 32 producers ----
    while (true) {
      unsigned f = load4_sc(faddr);
      WAITV(0);
      if (__all(f >= (unsigned)t)) break;
      __builtin_amdgcn_s_sleep(1);
    }

    // ---- h_t @ U: 16 PLAIN cached loads (L2-served broadcast), counted vmcnt ----
    const uint64_t hb = hbB + (uint64_t)(t & (NSLOT - 1)) * SLAB + hlane;
    uint32x4 abuf[16];
#pragma unroll
    for (int s = 0; s < 16; ++s) abuf[s] = load16_plain(hb + (uint64_t)s * 2048);
    WAITV(12); __builtin_amdgcn_sched_barrier(0);
    HMFMA(0); HMFMA(1); HMFMA(2); HMFMA(3);
    WAITV(8); __builtin_amdgcn_sched_barrier(0);
    HMFMA(4); HMFMA(5); HMFMA(6); HMFMA(7);
    WAITV(4); __builtin_amdgcn_sched_barrier(0);
    HMFMA(8); HMFMA(9); HMFMA(10); HMFMA(11);
    WAITV(0); __builtin_amdgcn_sched_barrier(0);
    HMFMA(12); HMFMA(13); HMFMA(14); HMFMA(15);

    // ---- K-split partial -> LDS (C layout: col=l&31, row=(r&3)+8*(r>>2)+4*q) ----
#pragma unroll
    for (int r = 0; r < 16; ++r) {
      int rl = (r & 3) + 8 * (r >> 2) + 4 * q;
      zp[ks * 2112 + (m_t * 32 + rl) * 33 + cl] = acc[r];
    }
    __syncthreads();

    // ---- reduce partials + gates: one thread per (batch, unit) ----
    float zi = bi, zf = bf_, zg = bg, zo = bo;
#pragma unroll
    for (int k2 = 0; k2 < 4; ++k2) {
      const float* zr = zp + k2 * 2112 + pb * 33;
      zi += zr[pu]; zf += zr[pu + 8]; zg += zr[pu + 16]; zo += zr[pu + 24];
    }
    float ig = sigm(zi), fg = sigm(zf), og = sigm(zo);
    float gg = fast_tanh(zg);
    c_reg = fg * c_reg + ig * gg;
    float h = og * fast_tanh(c_reg);

    // ---- in-register pack: 8 lanes' u16 h -> 16B on leader lanes ----
    unsigned hval = (unsigned)f2bf(h);
    unsigned other = __shfl_xor(hval, 1);
    unsigned pair32 = (l & 1) ? ((other & 0xffffu) | (hval << 16))
                              : ((hval & 0xffffu) | (other << 16));
    int base = l & ~7;
    uint32x4 hv;
    hv[0] = __shfl(pair32, base);
    hv[1] = __shfl(pair32, base + 2);
    hv[2] = __shfl(pair32, base + 4);
    hv[3] = __shfl(pair32, base + 6);

    // ---- publish h_{t+1} into slab (t+1)%128: sc1, all 8 waves in parallel ----
    const uint64_t hbn = hbB + (uint64_t)((t + 1) & (NSLOT - 1)) * SLAB;
    if ((l & 7) == 0) store16_sc(hbn + puboff, hv);
    if (t == T_STEPS - 1) {
      float* orow = out + (size_t)pb * 3072 + j0 + pu;
      orow[0]    = h;       // h_T
      orow[1024] = h;       // h_T again
      orow[2048] = c_reg;   // c_T
    }
    WAITV(0);          // ack this wave's publish (and epilogue stores, last step)
    __syncthreads();   // all waves acked; zp reads done
    if (tid == 0) store4_sc(fbase + (uint64_t)bid * 16, (unsigned)(t + 1));
  }
#undef HMFMA
}

extern "C" void kernel_launch(void* const* d_in, const int* in_sizes, int n_in,
                              void* d_out, int out_size, void* d_ws, size_t ws_size,
                              hipStream_t stream) {
  const float* x = (const float*)d_in[0];
  const float* W = (const float*)d_in[1];
  const float* U = (const float*)d_in[2];
  const float* b = (const float*)d_in[3];
  float* out = (float*)d_out;

  if (ws_size < WS_NEED) return;  // loud failure: output stays poisoned

  u16* xb = (u16*)d_ws;

  // zero slab 0 (h_0) + flags — replayed every graph launch
  hipMemsetAsync((char*)d_ws + HB_OFF, 0, SLAB, stream);
  hipMemsetAsync((char*)d_ws + FLG_OFF, 0, FLG_BYTES, stream);
  cvt_x<<<(T_STEPS * BATCH * DIN / 8 + 255) / 256, 256, 0, stream>>>(x, xb);
  lstm_kernel<<<NBLK, THREADS, 0, stream>>>(W, U, b, xb, (char*)d_ws, out);
}

// Round 20
// 2509.200 us; speedup vs baseline: 1.4397x; 1.0115x over previous
//
#include <hip/hip_runtime.h>
#include <stdint.h>

typedef unsigned short u16;

#define T_STEPS 512
#define BATCH   64
#define DIN     512
#define HID     1024
#define G4      4096
#define NBLK    128
#define NH      8       // hidden units per block
#define NC      32      // gate columns per block (4*NH)
#define THREADS 512

#define U_LD    1032    // 1024 + 8 pad (init staging only)
#define W_LD    520     // 512 + 8 pad  (init staging only)

// LDS: init phase  Ut[NC*U_LD] @0 (66048B), Wt[NC*W_LD] @66048 (33280B)
//      run  phase  zpart f32[4][64][33] @0 (33792B)
#define SM_BYTES 99328
#define WT_OFF   66048

// ws map
#define XB_BYTES ((size_t)T_STEPS * BATCH * DIN * 2)   // 32 MB bf16 x
#define HB_OFF   XB_BYTES        // rolling h slabs: [slot128][kblk128][row64][8u] bf16
#define SLAB     131072          // one slab = BATCH*HID*2 = 128 KB
#define NSLOT    128             // write-once window; reuse after 128 steps
#define HB_BYTES ((size_t)NSLOT * SLAB)                // 16 MB
#define FLG_OFF  (HB_OFF + HB_BYTES)                   // PACKED u32[128] = 512B (8 lines)
#define FLG_BYTES 2048
#define WS_NEED  (FLG_OFF + FLG_BYTES)

typedef float f32x16 __attribute__((ext_vector_type(16)));
typedef short bf16x8 __attribute__((ext_vector_type(8)));
typedef unsigned uint32x4 __attribute__((ext_vector_type(4)));

__device__ __forceinline__ u16 f2bf(float f) {
  unsigned u = __float_as_uint(f);
  u += 0x7fffu + ((u >> 16) & 1u);   // RNE
  return (u16)(u >> 16);
}
__device__ __forceinline__ float sigm(float x) {
  return __builtin_amdgcn_rcpf(1.f + __expf(-x));
}
__device__ __forceinline__ float fast_tanh(float x) {
  return 1.f - 2.f * __builtin_amdgcn_rcpf(__expf(2.f * x) + 1.f);
}

// sc0 sc1 = coherence-point access (bypass L1/L2) — publish + flags.
// plain    = normal cached load — h reads (write-once rolling slabs make it safe).
__device__ __forceinline__ uint32x4 load16_plain(uint64_t addr) {
  uint32x4 d;
  asm volatile("global_load_dwordx4 %0, %1, off" : "=v"(d) : "v"(addr));
  return d;
}
__device__ __forceinline__ uint32x4 load16_sc(uint64_t addr) {
  uint32x4 d;
  asm volatile("global_load_dwordx4 %0, %1, off sc0 sc1" : "=v"(d) : "v"(addr));
  return d;
}
__device__ __forceinline__ void store16_sc(uint64_t addr, uint32x4 v) {
  asm volatile("global_store_dwordx4 %0, %1, off sc0 sc1" :: "v"(addr), "v"(v) : "memory");
}
__device__ __forceinline__ void store4_sc(uint64_t addr, unsigned v) {
  asm volatile("global_store_dword %0, %1, off sc0 sc1" :: "v"(addr), "v"(v) : "memory");
}
#define WAITV(n) asm volatile("s_waitcnt vmcnt(" #n ")" ::: "memory")

// x[B][T][D] fp32 -> xb[T][B][D] bf16  (also flushes L2s across graph replays)
__global__ void cvt_x(const float* __restrict__ x, u16* __restrict__ xb) {
  int i = blockIdx.x * 256 + threadIdx.x;
  int dblk = i & 63;
  int rest = i >> 6;
  int b = rest & 63;
  int t = rest >> 6;
  const float4* s = reinterpret_cast<const float4*>(x + ((size_t)(b * T_STEPS + t)) * DIN + dblk * 8);
  float4 f0 = s[0], f1 = s[1];
  uint4 o;
  o.x = (unsigned)f2bf(f0.x) | ((unsigned)f2bf(f0.y) << 16);
  o.y = (unsigned)f2bf(f0.z) | ((unsigned)f2bf(f0.w) << 16);
  o.z = (unsigned)f2bf(f1.x) | ((unsigned)f2bf(f1.y) << 16);
  o.w = (unsigned)f2bf(f1.z) | ((unsigned)f2bf(f1.w) << 16);
  *reinterpret_cast<uint4*>(xb + ((size_t)(t * BATCH + b)) * DIN + dblk * 8) = o;
}

// Persistent LSTM (r19 skeleton). Block bid owns hidden units [bid*8, bid*8+8).
// GEMM: 32x32x16 MFMA, 8 waves = 2 M-tiles x 4 K-splits; B-frags in registers;
// K-split partials reduced through LDS (zp). h in write-once rolling slabs,
// consumed with plain cached loads (L2/L3-coalesced broadcast). NEW vs r19:
// flags are PACKED u32[128]; a wave polls its 32 producers through a shared
// 128B window -> the wave's poll coalesces to 2 CP line-requests (was 16),
// cutting coherence-point poll congestion ~8x at identical semantics.
__launch_bounds__(THREADS)
__global__ void lstm_kernel(const float* __restrict__ W, const float* __restrict__ U,
                            const float* __restrict__ bias, const u16* __restrict__ xb,
                            char* __restrict__ ws, float* __restrict__ out) {
  __shared__ __align__(16) char smraw[SM_BYTES];
  u16* Ut = (u16*)smraw;
  u16* Wt = (u16*)(smraw + WT_OFF);
  float* zp = (float*)smraw;              // run phase: [4][64][33]

  const int tid = threadIdx.x;
  const int bid = blockIdx.x;
  const int j0 = bid * NH;

  // ---- init: stage transposed bf16 weight slices ----
  for (int idx = tid; idx < NC * HID; idx += THREADS) {
    int c = idx & (NC - 1);
    int k = idx >> 5;
    int gcol = ((c >> 3) << 10) + j0 + (c & 7);
    Ut[c * U_LD + k] = f2bf(U[(size_t)k * G4 + gcol]);
  }
  for (int idx = tid; idx < NC * DIN; idx += THREADS) {
    int c = idx & (NC - 1);
    int k = idx >> 5;
    int gcol = ((c >> 3) << 10) + j0 + (c & 7);
    Wt[c * W_LD + k] = f2bf(W[(size_t)k * G4 + gcol]);
  }
  __syncthreads();

  // ---- wave geometry: wv = (ks<<1)|m_t ----
  const int l   = tid & 63;
  const int wv  = tid >> 6;
  const int m_t = wv & 1;          // batch rows m_t*32 .. +31
  const int ks  = wv >> 1;         // K-split 0..3 (256 of HID, 128 of DIN each)
  const int cl  = l & 31;          // A row within tile / B column
  const int q   = l >> 5;          // k-half of fragment

  // ---- persistent B fragments -> registers ----
  bf16x8 ubf[16], wbf[8];
  {
    const u16* ub = Ut + cl * U_LD + ks * 256 + q * 8;
#pragma unroll
    for (int s = 0; s < 16; ++s) ubf[s] = *(const bf16x8*)(ub + s * 16);
    const u16* wb = Wt + cl * W_LD + ks * 128 + q * 8;
#pragma unroll
    for (int s = 0; s < 8; ++s) wbf[s] = *(const bf16x8*)(wb + s * 16);
  }
  __syncthreads();   // staging dead; zp live from here

  const int row = m_t * 32 + cl;   // batch row this lane loads for A
  // gates: thread -> (row pb, unit pu)
  const int pb = tid >> 3;
  const int pu = tid & 7;
  float c_reg = 0.f;
  const float bi  = bias[j0 + pu];
  const float bf_ = bias[1024 + j0 + pu];
  const float bg  = bias[2048 + j0 + pu];
  const float bo  = bias[3072 + j0 + pu];

  const uint64_t hbB   = (uint64_t)ws + HB_OFF;
  const uint64_t fbase = (uint64_t)ws + FLG_OFF;
  // poll window: this wave's 32 producers = flags[ks*32 .. ks*32+31] (128B);
  // every lane reads 16B at (l&7)*16 -> whole wave touches only 2 cache lines
  const uint64_t faddr = fbase + (uint64_t)ks * 128 + (uint64_t)(l & 7) * 16;
  // h A-frag: kblk = ks*32 + s*2 + q, byte = kblk*1024 + row*16
  const uint64_t hlane = (uint64_t)(ks * 32 + q) * 1024 + (uint64_t)row * 16;
  // publish: leader lanes (l&7)==0 store 16B of row wv*8 + (l>>3)
  const uint64_t puboff = (uint64_t)bid * 1024 + (uint64_t)(wv * 8 + (l >> 3)) * 16;

#define HMFMA(S) acc = __builtin_amdgcn_mfma_f32_32x32x16_bf16( \
    __builtin_bit_cast(bf16x8, abuf[S]), ubf[S], acc, 0, 0, 0)

  for (int t = 0; t < T_STEPS; ++t) {
    f32x16 acc = {0.f,0.f,0.f,0.f,0.f,0.f,0.f,0.f,0.f,0.f,0.f,0.f,0.f,0.f,0.f,0.f};

    // ---- x_t @ W (cached loads; overlaps other blocks finishing t-1) ----
    const u16* xa = xb + (size_t)t * (BATCH * DIN) + row * DIN + ks * 128 + q * 8;
#pragma unroll
    for (int s = 0; s < 8; ++s) {
      bf16x8 av = *(const bf16x8*)(xa + s * 16);
      acc = __builtin_amdgcn_mfma_f32_32x32x16_bf16(av, wbf[s], acc, 0, 0, 0);
    }

    // ---- coalesced poll: 4 packed flags per lane, 2 lines per wave ----
    while (true) {
      uint32x4 f = load16_sc(faddr);
      WAITV(0);
      bool ok = (f[0] >= (unsigned)t) & (f[1] >= (unsigned)t) &
                (f[2] >= (unsigned)t) & (f[3] >= (unsigned)t);
      if (__all(ok)) break;
      __builtin_amdgcn_s_sleep(1);
    }

    // ---- h_t @ U: 16 PLAIN cached loads (L2-served broadcast), counted vmcnt ----
    const uint64_t hb = hbB + (uint64_t)(t & (NSLOT - 1)) * SLAB + hlane;
    uint32x4 abuf[16];
#pragma unroll
    for (int s = 0; s < 16; ++s) abuf[s] = load16_plain(hb + (uint64_t)s * 2048);
    WAITV(12); __builtin_amdgcn_sched_barrier(0);
    HMFMA(0); HMFMA(1); HMFMA(2); HMFMA(3);
    WAITV(8); __builtin_amdgcn_sched_barrier(0);
    HMFMA(4); HMFMA(5); HMFMA(6); HMFMA(7);
    WAITV(4); __builtin_amdgcn_sched_barrier(0);
    HMFMA(8); HMFMA(9); HMFMA(10); HMFMA(11);
    WAITV(0); __builtin_amdgcn_sched_barrier(0);
    HMFMA(12); HMFMA(13); HMFMA(14); HMFMA(15);

    // ---- K-split partial -> LDS (C layout: col=l&31, row=(r&3)+8*(r>>2)+4*q) ----
#pragma unroll
    for (int r = 0; r < 16; ++r) {
      int rl = (r & 3) + 8 * (r >> 2) + 4 * q;
      zp[ks * 2112 + (m_t * 32 + rl) * 33 + cl] = acc[r];
    }
    __syncthreads();

    // ---- reduce partials + gates: one thread per (batch, unit) ----
    float zi = bi, zf = bf_, zg = bg, zo = bo;
#pragma unroll
    for (int k2 = 0; k2 < 4; ++k2) {
      const float* zr = zp + k2 * 2112 + pb * 33;
      zi += zr[pu]; zf += zr[pu + 8]; zg += zr[pu + 16]; zo += zr[pu + 24];
    }
    float ig = sigm(zi), fg = sigm(zf), og = sigm(zo);
    float gg = fast_tanh(zg);
    c_reg = fg * c_reg + ig * gg;
    float h = og * fast_tanh(c_reg);

    // ---- in-register pack: 8 lanes' u16 h -> 16B on leader lanes ----
    unsigned hval = (unsigned)f2bf(h);
    unsigned other = __shfl_xor(hval, 1);
    unsigned pair32 = (l & 1) ? ((other & 0xffffu) | (hval << 16))
                              : ((hval & 0xffffu) | (other << 16));
    int base = l & ~7;
    uint32x4 hv;
    hv[0] = __shfl(pair32, base);
    hv[1] = __shfl(pair32, base + 2);
    hv[2] = __shfl(pair32, base + 4);
    hv[3] = __shfl(pair32, base + 6);

    // ---- publish h_{t+1} into slab (t+1)%128: sc1, all 8 waves in parallel ----
    const uint64_t hbn = hbB + (uint64_t)((t + 1) & (NSLOT - 1)) * SLAB;
    if ((l & 7) == 0) store16_sc(hbn + puboff, hv);
    if (t == T_STEPS - 1) {
      float* orow = out + (size_t)pb * 3072 + j0 + pu;
      orow[0]    = h;       // h_T
      orow[1024] = h;       // h_T again
      orow[2048] = c_reg;   // c_T
    }
    WAITV(0);          // ack this wave's publish (and epilogue stores, last step)
    __syncthreads();   // all waves acked; zp reads done
    if (tid == 0) store4_sc(fbase + (uint64_t)bid * 4, (unsigned)(t + 1));
  }
#undef HMFMA
}

extern "C" void kernel_launch(void* const* d_in, const int* in_sizes, int n_in,
                              void* d_out, int out_size, void* d_ws, size_t ws_size,
                              hipStream_t stream) {
  const float* x = (const float*)d_in[0];
  const float* W = (const float*)d_in[1];
  const float* U = (const float*)d_in[2];
  const float* b = (const float*)d_in[3];
  float* out = (float*)d_out;

  if (ws_size < WS_NEED) return;  // loud failure: output stays poisoned

  u16* xb = (u16*)d_ws;

  // zero slab 0 (h_0) + flags — replayed every graph launch
  hipMemsetAsync((char*)d_ws + HB_OFF, 0, SLAB, stream);
  hipMemsetAsync((char*)d_ws + FLG_OFF, 0, FLG_BYTES, stream);
  cvt_x<<<(T_STEPS * BATCH * DIN / 8 + 255) / 256, 256, 0, stream>>>(x, xb);
  lstm_kernel<<<NBLK, THREADS, 0, stream>>>(W, U, b, xb, (char*)d_ws, out);
}